// Round 11
// baseline (150.450 us; speedup 1.0000x reference)
//
#include <hip/hip_runtime.h>
#include <stdint.h>

using f16 = _Float16;

typedef _Float16 f16x8 __attribute__((ext_vector_type(8)));
typedef _Float16 f16x4 __attribute__((ext_vector_type(4)));
typedef float f32x4 __attribute__((ext_vector_type(4)));

#define LOG2E 1.44269504088896340736f

__device__ __forceinline__ f16 f2h(float f) { return (f16)f; }  // RNE

#if __has_builtin(__builtin_amdgcn_exp2f)
__device__ __forceinline__ float fexp2(float x) { return __builtin_amdgcn_exp2f(x); }
#else
__device__ __forceinline__ float fexp2(float x) { return exp2f(x); }
#endif

typedef __attribute__((address_space(1))) const uint32_t gu32;
typedef __attribute__((address_space(3))) uint32_t lu32;

__device__ __forceinline__ void dma16(const void* g, void* l) {
  // global->LDS DMA, 16 B/lane. Global source is PER-LANE (arbitrary per-lane
  // address); LDS dest is wave-uniform base + lane*16 auto-stride.
  __builtin_amdgcn_global_load_lds((gu32*)g, (lu32*)l, 16, 0, 0);
}

__device__ __forceinline__ f16x8 cvt8(const float* p) {
  const float4 a = *(const float4*)p;
  const float4 b = *(const float4*)(p + 4);
  f16x8 r;
  r[0] = (f16)a.x; r[1] = (f16)a.y; r[2] = (f16)a.z; r[3] = (f16)a.w;
  r[4] = (f16)b.x; r[5] = (f16)b.y; r[6] = (f16)b.z; r[7] = (f16)b.w;
  return r;
}

// B=4, C=64, N=4096.  Global in/out FP32; internal tensor-core path FP16.
// ws layout (bytes):
//   0     qa  f16 [4][4096][64]      (2 MB)  q*log2e, position-major
//   2 MB  ka2 f16 [4][8][4096][8]    (2 MB)  K channel-chunked: [b][c8][key][8c]
//                                            (PLAIN key order: the attn DMA
//                                            bakes the PV permutation into
//                                            its per-lane source addresses)
//   4 MB  va3 f16 [4][512][64][8]    (2 MB)  V key-chunked: [b][k8][c][8k]
//   6 MB  y0  f32 [4][64][4096]      (4 MB)  gamma*attn_out, pre-BN
//   10 MB stats: gs1[64] | gs2[64]   (zeroed by pre block 0)

// ---------------------------------------------------------------------------
// pre v3 (r7, ka2 back to plain order): 1024 blocks x 256 thr, 16-pos tiles.
// ---------------------------------------------------------------------------
__global__ __launch_bounds__(256, 2) void pam_pre(
    const float* __restrict__ x, const float* __restrict__ qw,
    const float* __restrict__ kw, const float* __restrict__ vw,
    const float* __restrict__ vb,
    f16* __restrict__ qa, f16* __restrict__ ka2, f16* __restrict__ va3,
    float* __restrict__ gz)
{
  __shared__ alignas(16) f16 xt[16 * 72];   // xt[n][c] f16, row stride 72
  const int tid = threadIdx.x;
  const int b = blockIdx.x >> 8;
  const int n0 = (blockIdx.x & 255) << 4;
  const int lane = tid & 63;
  const int wv = tid >> 6;
  const int quad = lane >> 4, l15 = lane & 15;

  if (blockIdx.x == 0 && tid < 128) gz[tid] = 0.f;   // gs1|gs2 zero-init

  // stage x[b][c][n0:+16] (fp32) transposed into xt[n][c] (f16)
  {
    const int c = tid >> 2;
    const int j0 = (tid & 3) << 2;
    const float4 v0 = *(const float4*)(x + ((size_t)(b * 64 + c) << 12) + n0 + j0);
    xt[(j0 + 0) * 72 + c] = f2h(v0.x);
    xt[(j0 + 1) * 72 + c] = f2h(v0.y);
    xt[(j0 + 2) * 72 + c] = f2h(v0.z);
    xt[(j0 + 3) * 72 + c] = f2h(v0.w);
  }
  __syncthreads();

  // conv over channel axis (SAME, zero pad): 128 threads, 8 channels each
  if (tid < 128) {
    const float qw0 = qw[0], qw1 = qw[1], qw2 = qw[2];
    const float kw0 = kw[0], kw1 = kw[1], kw2 = kw[2];
    const int n = tid >> 3;            // 0..15
    const int c8 = tid & 7;            // 0..7
    const f16x8 v0 = *(const f16x8*)&xt[n * 72 + c8 * 8];
    const float lm = (c8 > 0) ? (float)xt[n * 72 + c8 * 8 - 1] : 0.f;
    const float rp = (c8 < 7) ? (float)xt[n * 72 + c8 * 8 + 8] : 0.f;
    f16x8 qv8, kv8;
#pragma unroll
    for (int j = 0; j < 8; ++j) {
      const float xm = (j == 0) ? lm : (float)v0[j - 1];
      const float x0 = (float)v0[j];
      const float xp = (j == 7) ? rp : (float)v0[j + 1];
      qv8[j] = f2h((qw0 * xm + qw1 * x0 + qw2 * xp) * LOG2E);  // log2-domain
      kv8[j] = f2h(kw0 * xm + kw1 * x0 + kw2 * xp);
    }
    const int nn = n0 + n;
    *(f16x8*)(qa + ((size_t)((b << 12) + nn) << 6) + c8 * 8) = qv8;
    *(f16x8*)(ka2 + (((size_t)(b * 8 + c8)) << 15) + (nn << 3)) = kv8;
  }

  // v^T[n][co] via mfma; wave wv -> co columns [16wv,+16)
  {
    const f16x8 a0 = *(const f16x8*)&xt[l15 * 72 + quad * 8];
    const f16x8 a1 = *(const f16x8*)&xt[l15 * 72 + quad * 8 + 32];
    const int co = wv * 16 + l15;
    const f16x8 b0 = cvt8(vw + co * 64 + quad * 8);
    const f16x8 b1 = cvt8(vw + co * 64 + quad * 8 + 32);
    f32x4 z = {0.f, 0.f, 0.f, 0.f};
    z = __builtin_amdgcn_mfma_f32_16x16x32_f16(a0, b0, z, 0, 0, 0);
    z = __builtin_amdgcn_mfma_f32_16x16x32_f16(a1, b1, z, 0, 0, 0);
    const float vbv = vb[co];
    f16x4 pv;
#pragma unroll
    for (int r = 0; r < 4; ++r) pv[r] = f2h(z[r] + vbv);
    const int nb = n0 + quad * 4;      // 4 consecutive n per thread
    *(f16x4*)(va3 + (((size_t)(b * 512 + (nb >> 3))) << 9)
              + (co << 3) + (nb & 7)) = pv;
  }
}

// ---------------------------------------------------------------------------
// attention v25: WAVE-PRIVATE staging, ZERO barriers in the main loop.
//  - r7's dataflow (512 thr, 128-key tiles, V global->VGPR, O^T PV via
//    16x16x32, lane-local softmax + defer-max) but each wave stages ONLY its
//    own 32-key x 64c K slice (4 KB) into a private double-buffered LDS
//    region via 4 dma16 with PER-LANE-PERMUTED global sources: lane covers
//    c8 = 2p+(lane>>5), LDS slot s = lane&31 holds key kmap(s) =
//    ((s&15)>>2)*8 + (s&3) + (s>>4)*4 -- the PV-k-order permutation is baked
//    into the DMA, so LDS reads are LINEAR and S^T regs land in PV B-frag
//    order with zero shuffles (same invariant as r7, new mechanism).
//  - sync is per-wave counted vmcnt only (in-order retirement):
//    top-of-iter vmcnt(4) retires DMA(t) [V(t) issued after, stays in
//    flight]; compiler's own V-wait before PV retires V(t); DMA(t+1) gets
//    softmax+PV+next-V-issue of cover.  NO s_barrier, NO reconvergence:
//    waves free-run -- the 8-wave convoy (r10's diagnosis) is gone.
//  - K staged per-wave means qh 0/1 duplicate staging (2 MB/block total);
//    1 GB L2->LDS chip-wide, well under the 34.5 TB/s L2 ceiling.
//  - LDS: 8 waves x 8 KB kbuf + 8.3 KB ldsO + 1.2 KB stats = 73.5 KB
//    -> 2 blocks/CU (launch_bounds(512,4)).
// ---------------------------------------------------------------------------
__global__ __launch_bounds__(512, 4) void pam_attn(
    const f16* __restrict__ qa, const f16* __restrict__ ka2,
    const f16* __restrict__ va3, const float* __restrict__ gam,
    float* __restrict__ y0, float* __restrict__ gs1, float* __restrict__ gs2)
{
  __shared__ alignas(16) f16 kbuf[8][4096];   // 8 KB per wave, 2x4KB buffers
  __shared__ float ldsO[32 * 65];             // [q][c], pad 65
  __shared__ float ldsM[4][32], ldsL[4][32], ldsMg[32], ldsInv[32];

  const int tid = threadIdx.x;
  const int wv = tid >> 6, lane = tid & 63;
  const int quad = lane >> 4, l15 = lane & 15;
  const int ks = wv & 3, qh = wv >> 2;
  const int b = blockIdx.x & 3;
  const int qb = blockIdx.x >> 2;          // 0..127
  const int qb0 = qb << 5;
  const int phase = qb & 31;               // L2-spread rotation (32 tiles)

  for (int i = tid; i < 32 * 65; i += 512) ldsO[i] = 0.f;
  __syncthreads();                         // ldsO zeroed before merge use

  const int bn = b << 12;
  // Q fragments (B-operand: col=l15=q, k=quad*8+j over channels)
  f16x8 bq0, bq1;
  {
    const int q = qb0 + qh * 16 + l15;
    const f16* qp = qa + ((size_t)(bn + q) << 6) + quad * 8;
    bq0 = *(const f16x8*)qp;
    bq1 = *(const f16x8*)(qp + 32);
  }

  // per-lane K DMA source: c8 = 2p + (lane>>5), key = ks*32 + kmap(lane&31)
  // kmap(s) = ((s&15)>>2)*8 + (s&3) + (s>>4)*4  (bakes PV k-order into LDS)
  const int s31 = lane & 31;
  const int kmap = (((s31 & 15) >> 2) << 3) + (s31 & 3) + ((s31 >> 4) << 2);
  const f16* kgs = ka2 + (((size_t)(b * 8 + (lane >> 5))) << 15)
                 + ((ks * 32 + kmap) << 3);
  f16* const kwv = kbuf[wv];               // this wave's private 8 KB

  // V per-lane global base: va3[b][k8 = 16*g + ks*4 + quad][c][8k], +l15*8
  const f16* vgp = va3 + ((size_t)b << 18) + ((ks * 4 + quad) << 9) + (l15 << 3);

  f32x4 o[4] = {};                 // O^T: col=l15=q, row c = ct*16+quad*4+r
  float m = -1e30f, lp = 0.f;

  // K reads are linear: koff selects (c8=quad) region, +1024 -> c8=4+quad,
  // +128 -> key slot +16 (second S^T row-tile)
  const int koff = ((quad >> 1) << 9) + ((quad & 1) << 8) + (l15 << 3);

  // prologue: stage tile 'phase' into buffer 0 (4 dma16 outstanding)
  {
    const f16* src = kgs + ((size_t)phase << 10);
    dma16(src,          kwv);
    dma16(src + 65536,  kwv + 512);
    dma16(src + 131072, kwv + 1024);
    dma16(src + 196608, kwv + 1536);
  }

#pragma unroll 1
  for (int kt = 0; kt < 32; ++kt) {
    const int cur = kt & 1;
    const int gcur = (kt + phase) & 31;

    // V fragments for THIS tile: issued first (younger than DMA(t))
    const f16* vt = vgp + ((size_t)gcur << 13);
    const f16x8 av0 = *(const f16x8*)(vt);
    const f16x8 av1 = *(const f16x8*)(vt + 128);
    const f16x8 av2 = *(const f16x8*)(vt + 256);
    const f16x8 av3 = *(const f16x8*)(vt + 384);
    __builtin_amdgcn_sched_barrier(0);

    // retire DMA(t) (oldest 4 of <=8 outstanding); V(t) stays in flight
    asm volatile("s_waitcnt vmcnt(4)" ::: "memory");
    __builtin_amdgcn_sched_barrier(0);

    // linear K reads from this wave's private buffer
    const f16* kc = kwv + (cur << 11);
    const f16x8 ak00 = *(const f16x8*)(kc + koff);
    const f16x8 ak01 = *(const f16x8*)(kc + koff + 1024);
    const f16x8 ak10 = *(const f16x8*)(kc + koff + 128);
    const f16x8 ak11 = *(const f16x8*)(kc + koff + 1152);

    // S^T[32 key (kmap-permuted)][16 q], contraction over 64 channels
    f32x4 z0, z1;
    {
      f32x4 z = {0.f, 0.f, 0.f, 0.f};
      z = __builtin_amdgcn_mfma_f32_16x16x32_f16(ak00, bq0, z, 0, 0, 0);
      z0 = __builtin_amdgcn_mfma_f32_16x16x32_f16(ak01, bq1, z, 0, 0, 0);
    }
    {
      f32x4 z = {0.f, 0.f, 0.f, 0.f};
      z = __builtin_amdgcn_mfma_f32_16x16x32_f16(ak10, bq0, z, 0, 0, 0);
      z1 = __builtin_amdgcn_mfma_f32_16x16x32_f16(ak11, bq1, z, 0, 0, 0);
    }

    // prefetch K(t+1) into the other private buffer (self-paced)
    if (kt < 31) {
      const int tn = (kt + 1 + phase) & 31;
      const f16* src = kgs + ((size_t)tn << 10);
      f16* dst = kwv + ((cur ^ 1) << 11);
      dma16(src,          dst);
      dma16(src + 65536,  dst + 512);
      dma16(src + 131072, dst + 1024);
      dma16(src + 196608, dst + 1536);
    }

    // online softmax: lane holds keys quad*8+{0..7} for query q=l15
    float tmax = fmaxf(fmaxf(fmaxf(z0[0], z0[1]), fmaxf(z0[2], z0[3])),
                       fmaxf(fmaxf(z1[0], z1[1]), fmaxf(z1[2], z1[3])));
    tmax = fmaxf(tmax, __shfl_xor(tmax, 16, 64));
    tmax = fmaxf(tmax, __shfl_xor(tmax, 32, 64));
    const bool need = !__all(tmax <= m + 8.f);    // defer-max, THR=8
    const float mn = need ? fmaxf(m, tmax) : m;

    const float p0 = fexp2(z0[0] - mn);
    const float p1 = fexp2(z0[1] - mn);
    const float p2 = fexp2(z0[2] - mn);
    const float p3 = fexp2(z0[3] - mn);
    const float p4 = fexp2(z1[0] - mn);
    const float p5 = fexp2(z1[1] - mn);
    const float p6 = fexp2(z1[2] - mn);
    const float p7 = fexp2(z1[3] - mn);
    const float ts = ((p0 + p1) + (p2 + p3)) + ((p4 + p5) + (p6 + p7));

    f16x8 pa;   // P^T B-frag: k-order == reg order (kmap guarantees it)
    pa[0] = f2h(p0); pa[1] = f2h(p1); pa[2] = f2h(p2); pa[3] = f2h(p3);
    pa[4] = f2h(p4); pa[5] = f2h(p5); pa[6] = f2h(p6); pa[7] = f2h(p7);

    if (need) {
      const float al = fexp2(m - mn);   // lane-local (q in column)
      lp = lp * al + ts;
      m = mn;
#pragma unroll
      for (int ct = 0; ct < 4; ++ct)
        for (int r = 0; r < 4; ++r) o[ct][r] *= al;
    } else {
      lp += ts;
    }

    // O^T += V * P^T (V from registers; compiler's V-wait retires V(t)
    // in-order, leaving DMA(t+1) in flight -- no barrier, no drain)
    o[0] = __builtin_amdgcn_mfma_f32_16x16x32_f16(av0, pa, o[0], 0, 0, 0);
    o[1] = __builtin_amdgcn_mfma_f32_16x16x32_f16(av1, pa, o[1], 0, 0, 0);
    o[2] = __builtin_amdgcn_mfma_f32_16x16x32_f16(av2, pa, o[2], 0, 0, 0);
    o[3] = __builtin_amdgcn_mfma_f32_16x16x32_f16(av3, pa, o[3], 0, 0, 0);
  }

  // drain any trailing VMEM before cross-wave LDS phases
  asm volatile("s_waitcnt vmcnt(0)" ::: "memory");

  // publish per-wave online state (m quad-uniform; lp reduced across quads)
  {
    float v = lp;
    v += __shfl_xor(v, 16, 64);
    v += __shfl_xor(v, 32, 64);
    if (quad == 0) {
      ldsM[ks][qh * 16 + l15] = m;
      ldsL[ks][qh * 16 + l15] = v;
    }
  }
  __syncthreads();

  // per-query global max + denom (4 key-slices)
  if (tid < 32) {
    const float M = fmaxf(fmaxf(ldsM[0][tid], ldsM[1][tid]),
                          fmaxf(ldsM[2][tid], ldsM[3][tid]));
    const float lt = ldsL[0][tid] * fexp2(ldsM[0][tid] - M) +
                     ldsL[1][tid] * fexp2(ldsM[1][tid] - M) +
                     ldsL[2][tid] * fexp2(ldsM[2][tid] - M) +
                     ldsL[3][tid] * fexp2(ldsM[3][tid] - M);
    ldsMg[tid] = M;
    ldsInv[tid] = 1.f / lt;
  }
  __syncthreads();

  // m-aware merge of partial O^T across the 4 key-split waves (sc lane-local)
  {
    const int q = qh * 16 + l15;
    const float sc = fexp2(m - ldsMg[q]);
#pragma unroll
    for (int ct = 0; ct < 4; ++ct)
      for (int r = 0; r < 4; ++r)
        atomicAdd(&ldsO[q * 65 + ct * 16 + quad * 4 + r], o[ct][r] * sc);
  }
  __syncthreads();

  // epilogue: y0[b][c][n] = gamma * O / l ; BN partial sums
  const float g = gam[0];
  {
    const int c = tid >> 3;              // 0..63
    const int q0 = (tid & 7) << 2;       // 0..28
    float4 v4;
    float* vp = &v4.x;
    float s1 = 0.f, s2 = 0.f;
    for (int r = 0; r < 4; ++r) {
      const float val = g * ldsO[(q0 + r) * 65 + c] * ldsInv[q0 + r];
      vp[r] = val; s1 += val; s2 += val * val;
    }
    *(float4*)(y0 + ((size_t)(b * 64 + c) << 12) + qb0 + q0) = v4;
    s1 += __shfl_xor(s1, 1, 64);
    s2 += __shfl_xor(s2, 1, 64);
    s1 += __shfl_xor(s1, 2, 64);
    s2 += __shfl_xor(s2, 2, 64);
    s1 += __shfl_xor(s1, 4, 64);
    s2 += __shfl_xor(s2, 4, 64);
    if ((tid & 7) == 0) {
      atomicAdd(&gs1[c], s1);
      atomicAdd(&gs2[c], s2);
    }
  }
}

// ---------------------------------------------------------------------------
// apply: BN(scale/shift from gs1/gs2) + residual.
// ---------------------------------------------------------------------------
__global__ __launch_bounds__(256, 2) void pam_apply(
    const float* __restrict__ y0, const float* __restrict__ x,
    const float* __restrict__ gs1, const float* __restrict__ gs2,
    const float* __restrict__ bnw, const float* __restrict__ bnb,
    float* __restrict__ out)
{
  const int i = (blockIdx.x * 256 + threadIdx.x) << 2;   // 4 elems/thread
  const int c = (i >> 12) & 63;
  const float inv_n = 1.f / 16384.f;
  const float mean = gs1[c] * inv_n;
  const float var = fmaxf(gs2[c] * inv_n - mean * mean, 0.f);
  const float sc = bnw[c] * rsqrtf(var + 1e-5f);
  const float sh = bnb[c] - mean * sc;
  const float4 y = *(const float4*)(y0 + i);
  const float4 xv = *(const float4*)(x + i);
  float4 r;
  r.x = y.x * sc + sh + xv.x;
  r.y = y.y * sc + sh + xv.y;
  r.z = y.z * sc + sh + xv.z;
  r.w = y.w * sc + sh + xv.w;
  *(float4*)(out + i) = r;
}

// ---------------------------------------------------------------------------
extern "C" void kernel_launch(void* const* d_in, const int* in_sizes, int n_in,
                              void* d_out, int out_size, void* d_ws, size_t ws_size,
                              hipStream_t stream)
{
  (void)in_sizes; (void)n_in; (void)out_size; (void)ws_size;
  const float* x   = (const float*)d_in[0];
  const float* qw  = (const float*)d_in[1];
  const float* kw  = (const float*)d_in[2];
  const float* vw  = (const float*)d_in[3];
  const float* vb  = (const float*)d_in[4];
  const float* gam = (const float*)d_in[5];
  const float* bnw = (const float*)d_in[6];
  const float* bnb = (const float*)d_in[7];

  char* ws = (char*)d_ws;
  f16*   qa  = (f16*)(ws);
  f16*   ka2 = (f16*)(ws + (2u << 20));
  f16*   va3 = (f16*)(ws + (4u << 20));
  float* y0  = (float*)(ws + (6u << 20));
  float* gs1 = (float*)(ws + (10u << 20));          // 64 floats
  float* gs2 = (float*)(ws + (10u << 20) + 256);    // 64 floats (contiguous)

  pam_pre  <<<1024, 256, 0, stream>>>(x, qw, kw, vw, vb, qa, ka2, va3, gs1);
  pam_attn <<<512, 512, 0, stream>>>(qa, ka2, va3, gam, y0, gs1, gs2);
  pam_apply<<<1024, 256, 0, stream>>>(y0, x, gs1, gs2, bnw, bnb, (float*)d_out);
}